// Round 8
// baseline (487.998 us; speedup 1.0000x reference)
//
#include <hip/hip_runtime.h>
#include <math.h>

// B=8192, X=8, C=512, P=8, Y=1000, FAKE=16, F=2048, CLS=1000, IN_DIM=1024, SF=64
//
// Pipeline (12 launches, r5 structure):
//  k_prep:   texn = rownorm(tex_f)->bf16  |  g_bf = fake_cls @ fc_w ->bf16
//  logits[p] = g_bf[p] @ texn[p]^T            [MFMA128 EPI3, z=p]
//  k_wsum_sm: softmax(logits) fused, partial texa sums
//  k_texa_red: reduce -> texa bf16
//  cp' = (img @ texa^T) * inv_row             [MFMA128 EPI0, A fp32 reg-staged,
//                                              row-norm inline, out bf16, permuted cols]
//  colstat(cp) -> bnfin1 -> foldw1 (perm)     [bf16 weights]
//  h = elu(cp' @ w1a^T + b1p)                 [gemm256 FM=8, stage-overlapped pipeline,
//                                              col-stats fused -> ps/pq (64 rows)]
//  bnfin2 -> foldw2 (pad 1024)                [bf16 weights]
//  out = h @ w2a^T + b2p                      [gemm256 FM=4, fp32]

typedef __attribute__((ext_vector_type(8))) short bf16x8;
typedef __attribute__((ext_vector_type(4))) float f32x4;

__device__ __forceinline__ float waveSum(float v) {
#pragma unroll
    for (int o = 32; o > 0; o >>= 1) v += __shfl_xor(v, o);
    return v;
}
__device__ __forceinline__ float waveMax(float v) {
#pragma unroll
    for (int o = 32; o > 0; o >>= 1) v = fmaxf(v, __shfl_xor(v, o));
    return v;
}
__device__ __forceinline__ unsigned short f2bf(float x) {
    union { float f; unsigned u; } v; v.f = x;
    unsigned r = v.u + 0x7FFFu + ((v.u >> 16) & 1u);
    return (unsigned short)(r >> 16);
}
__device__ __forceinline__ float bf2f(unsigned short h) {
    union { unsigned u; float f; } v; v.u = ((unsigned)h) << 16; return v.f;
}
__device__ __forceinline__ void gload16(const void* g, const void* l) {
    __builtin_amdgcn_global_load_lds((const __attribute__((address_space(1))) void*)g,
                                     (__attribute__((address_space(3))) void*)l, 16, 0, 0);
}
__device__ __forceinline__ int xcd_swz(int d, int n) {
    int q = n >> 3;                     // all gemm grids are %8==0
    return (d & 7) * q + (d >> 3);
}
#define SBAR __builtin_amdgcn_sched_barrier(0)

// ---------- fused: rownorm(tex_f)->texn bf16 (blocks 0..7999), g_bf (8000..8127) ----------
__global__ __launch_bounds__(256) void k_prep(const float* __restrict__ tex_f,
                                              unsigned short* __restrict__ texn,
                                              const float* __restrict__ fake_cls,
                                              const float* __restrict__ fc_w,
                                              unsigned short* __restrict__ g_bf) {
    __shared__ float sred[4];
    __shared__ float fcls[512];
    int bid = blockIdx.x, t = threadIdx.x;
    if (bid < 8000) {
        const float* r = tex_f + (size_t)bid * 512;
        float2 v = *(const float2*)(r + t * 2);
        float ss = v.x * v.x + v.y * v.y;
        ss = waveSum(ss);
        if ((t & 63) == 0) sred[t >> 6] = ss;
        __syncthreads();
        float tot = sred[0] + sred[1] + sred[2] + sred[3];
        float sc = 64.f / (sqrtf(tot) + 1e-6f);
        unsigned u = (unsigned)f2bf(v.x * sc) | ((unsigned)f2bf(v.y * sc) << 16);
        *(unsigned*)(texn + (size_t)bid * 512 + t * 2) = u;
    } else {
        int row = bid - 8000;
        fcls[t]       = fake_cls[row * 512 + t];
        fcls[t + 256] = fake_cls[row * 512 + t + 256];
        __syncthreads();
        float a0 = 0.f, a1 = 0.f;
        for (int d = 0; d < 512; ++d) {
            float fv = fcls[d];
            a0 = fmaf(fv, fc_w[d * 512 + t], a0);
            a1 = fmaf(fv, fc_w[d * 512 + t + 256], a1);
        }
        g_bf[row * 512 + t]       = f2bf(a0);
        g_bf[row * 512 + t + 256] = f2bf(a1);
    }
}

// ---------- wsum with fused softmax: block (yt 0..15, p 0..7) ----------
__global__ __launch_bounds__(256) void k_wsum_sm(const float* __restrict__ logit,
                                                 const unsigned short* __restrict__ texn,
                                                 float* __restrict__ part) {
    int yt = blockIdx.x, p = blockIdx.y, t = threadIdx.x;
    int lane = t & 63, w = t >> 6;
    __shared__ float wl[16][63];
    __shared__ float ms[16], iss[16];
    const int y0 = yt * 63;
    const int ylen = min(63, 1000 - y0);
#pragma unroll
    for (int rr = 0; rr < 4; ++rr) {
        int x = w * 4 + rr;
        const float* lr = logit + ((size_t)p * 16 + x) * 1000;
        float m = -3.0e38f;
        for (int y = lane; y < 1000; y += 64) m = fmaxf(m, lr[y]);
        m = waveMax(m);
        float s = 0.f;
        for (int y = lane; y < 1000; y += 64) s += expf(lr[y] - m);
        s = waveSum(s);
        if (lane == 0) { ms[x] = m; iss[x] = 1.f / s; }
    }
    __syncthreads();
    for (int idx = t; idx < 16 * ylen; idx += 256) {
        int x = idx / ylen, y = idx % ylen;
        wl[x][y] = expf(logit[((size_t)p * 16 + x) * 1000 + y0 + y] - ms[x]) * iss[x];
    }
    __syncthreads();
    int c0 = t * 2;
    const unsigned short* tp = texn + ((size_t)p * 1000 + y0) * 512 + c0;
    float a0[16], a1[16];
#pragma unroll
    for (int x = 0; x < 16; ++x) { a0[x] = 0.f; a1[x] = 0.f; }
    for (int y = 0; y < ylen; ++y) {
        unsigned u = *(const unsigned*)(tp + (size_t)y * 512);
        float lo = bf2f((unsigned short)(u & 0xffff));
        float hi = bf2f((unsigned short)(u >> 16));
#pragma unroll
        for (int x = 0; x < 16; ++x) {
            float ww = wl[x][y];
            a0[x] = fmaf(ww, lo, a0[x]);
            a1[x] = fmaf(ww, hi, a1[x]);
        }
    }
#pragma unroll
    for (int x = 0; x < 16; ++x) {
        float* dst = part + ((size_t)((yt * 8 + p) * 16 + x)) * 512 + c0;
        dst[0] = a0[x];
        dst[1] = a1[x];
    }
}

// ---------- reduce 16 y-partials -> texa bf16 ----------
__global__ __launch_bounds__(256) void k_texa_red(const float* __restrict__ part,
                                                  unsigned short* __restrict__ texa) {
    int row = blockIdx.x, t = threadIdx.x;      // row = p*16 + x
    int p = row >> 4, x = row & 15;
    int c = t * 2;
    float s0 = 0.f, s1 = 0.f;
#pragma unroll
    for (int yt = 0; yt < 16; ++yt) {
        const float* src = part + ((size_t)((yt * 8 + p) * 16 + x)) * 512 + c;
        s0 += src[0];
        s1 += src[1];
    }
    unsigned u = (unsigned)f2bf(s0) | ((unsigned)f2bf(s1) << 16);
    *(unsigned*)(texa + (size_t)row * 512 + c) = u;
}

// ---------- column stats over bf16 matrix (cp): 128 rows per y-block ----------
__global__ __launch_bounds__(256) void k_colstat_bf(const unsigned short* __restrict__ src,
                                                    float* __restrict__ ps,
                                                    float* __restrict__ pq, int ncols) {
    int col = blockIdx.x * 256 + threadIdx.x;
    int r0 = blockIdx.y * 128;
    const unsigned short* p = src + (size_t)r0 * ncols + col;
    float s = 0.f, q = 0.f;
    for (int r = 0; r < 128; ++r) {
        float v = bf2f(p[(size_t)r * ncols]);
        s += v;
        q = fmaf(v, v, q);
    }
    ps[(size_t)blockIdx.y * ncols + col] = s;
    pq[(size_t)blockIdx.y * ncols + col] = q;
}

// ---------- finalize BN scale/shift; PERM maps permuted col' -> true j ----------
template <bool PERM>
__global__ __launch_bounds__(256) void k_bnfin(const float* __restrict__ ps,
                                               const float* __restrict__ pq,
                                               const float* __restrict__ gam,
                                               const float* __restrict__ bet,
                                               float* __restrict__ a, float* __restrict__ c,
                                               int ncols) {
    int col = blockIdx.x * 256 + threadIdx.x;
    float S = 0.f, Q = 0.f;
    for (int i = 0; i < 64; ++i) {
        S += ps[(size_t)i * ncols + col];
        Q += pq[(size_t)i * ncols + col];
    }
    float mean = S * (1.f / 8192.f);
    float var = Q * (1.f / 8192.f) - mean * mean;
    int j = col;
    if (PERM) {
        int x = col >> 7, jj = col & 127, pp = jj >> 4, d = jj & 15;
        j = (pp << 7) + (x << 4) + d;
    }
    float av = gam[j] * rsqrtf(var + 1e-5f);
    a[col] = av;
    c[col] = bet[j] - mean * av;
}

// ---------- fold BN into weights -> bf16 ----------
template <bool PERM>
__global__ __launch_bounds__(256) void k_foldw_bf(const float* __restrict__ W,
                                                  const float* __restrict__ bin,
                                                  const float* __restrict__ a,
                                                  const float* __restrict__ c,
                                                  unsigned short* __restrict__ Wout,
                                                  float* __restrict__ bout,
                                                  int Kdim, int nvalid) {
    int f = blockIdx.x, t = threadIdx.x;
    unsigned short* wo = Wout + (size_t)f * Kdim;
    if (f >= nvalid) {
        for (int col = t; col < Kdim; col += 256) wo[col] = 0;
        if (t == 0) bout[f] = 0.f;
        return;
    }
    const float* wr = W + (size_t)f * Kdim;
    float partial = 0.f;
    for (int col = t; col < Kdim; col += 256) {
        int j = col;
        if (PERM) {
            int x = col >> 7, jj = col & 127, pp = jj >> 4, d = jj & 15;
            j = (pp << 7) + (x << 4) + d;
        }
        float wv = wr[j];
        wo[col] = f2bf(wv * a[col]);
        partial = fmaf(wv, c[col], partial);
    }
    partial = waveSum(partial);
    __shared__ float sred[4];
    if ((t & 63) == 0) sred[t >> 6] = partial;
    __syncthreads();
    if (t == 0) bout[f] = bin[f] + sred[0] + sred[1] + sred[2] + sred[3];
}

// ---------- small MFMA GEMM (128x128 tile, 4 waves) for cp & logits ----------
// EPI 0 (A_F32): bf16 store * rowinv computed inline from A's fp32 rows (cp)
// EPI 3: fp32 store, col<nvalid, row<16 (logits, batched over z=p)
template <int EPI, bool A_F32>
__global__ __launch_bounds__(256) void gemm_mfma(const void* __restrict__ Av,
                                                 const unsigned short* __restrict__ Bv,
                                                 void* __restrict__ Cv, int K,
                                                 int ntn, int ldc, int nvalid,
                                                 int aZ, int bZ, int cZ) {
    __shared__ unsigned short Asl[128 * 64];
    __shared__ unsigned short Bsl[128 * 64];
    __shared__ float rowinv[128];
    const int tid = threadIdx.x;
    const int lane = tid & 63, wid = tid >> 6;
    const int wr = wid >> 1, wc = wid & 1;
    const int wg = xcd_swz(blockIdx.x, gridDim.x);
    const int m0 = (wg / ntn) * 128, n0 = (wg % ntn) * 128;
    const int z = blockIdx.y;

    const float* Af = (const float*)Av;
    const unsigned short* Ab = (const unsigned short*)Av + (size_t)z * aZ;
    const unsigned short* B = Bv + (size_t)z * bZ;

    f32x4 acc[4][4];
#pragma unroll
    for (int i = 0; i < 4; ++i)
#pragma unroll
        for (int j = 0; j < 4; ++j) acc[i][j] = {0.f, 0.f, 0.f, 0.f};

    const int swz = ((lane & 7) ^ (lane >> 3)) * 8;
    const int lrow = lane & 15, lkh = lane >> 4;
    float ssq[4] = {0.f, 0.f, 0.f, 0.f};

    for (int k0 = 0; k0 < K; k0 += 64) {
        if (A_F32) {
#pragma unroll
            for (int r = 0; r < 4; ++r) {
                int row = r * 32 + (tid >> 3);
                int kk = (tid & 7) * 8;
                const float* src = Af + (size_t)(m0 + row) * K + k0 + kk;
                float4 p0 = *(const float4*)src;
                float4 p1 = *(const float4*)(src + 4);
                ssq[r] += p0.x*p0.x + p0.y*p0.y + p0.z*p0.z + p0.w*p0.w
                        + p1.x*p1.x + p1.y*p1.y + p1.z*p1.z + p1.w*p1.w;
                bf16x8 v;
                v[0] = (short)f2bf(p0.x); v[1] = (short)f2bf(p0.y);
                v[2] = (short)f2bf(p0.z); v[3] = (short)f2bf(p0.w);
                v[4] = (short)f2bf(p1.x); v[5] = (short)f2bf(p1.y);
                v[6] = (short)f2bf(p1.z); v[7] = (short)f2bf(p1.w);
                *(bf16x8*)&Asl[row * 64 + (kk ^ ((row & 7) << 3))] = v;
            }
        } else {
#pragma unroll
            for (int r = 0; r < 4; ++r) {
                int row = r * 32 + wid * 8 + (lane >> 3);
                gload16(Ab + (size_t)(m0 + row) * K + k0 + swz,
                        Asl + r * 2048 + wid * 512);
            }
        }
#pragma unroll
        for (int r = 0; r < 4; ++r) {
            int row = r * 32 + wid * 8 + (lane >> 3);
            gload16(B + (size_t)(n0 + row) * K + k0 + swz,
                    Bsl + r * 2048 + wid * 512);
        }
        __syncthreads();
#pragma unroll
        for (int kk = 0; kk < 2; ++kk) {
            bf16x8 af[4], bfr[4];
#pragma unroll
            for (int m = 0; m < 4; ++m) {
                int row = wr * 64 + m * 16 + lrow;
                af[m] = *(const bf16x8*)&Asl[row * 64 + ((kk * 32 + lkh * 8) ^ ((row & 7) << 3))];
            }
#pragma unroll
            for (int n = 0; n < 4; ++n) {
                int row = wc * 64 + n * 16 + lrow;
                bfr[n] = *(const bf16x8*)&Bsl[row * 64 + ((kk * 32 + lkh * 8) ^ ((row & 7) << 3))];
            }
#pragma unroll
            for (int m = 0; m < 4; ++m)
#pragma unroll
                for (int n = 0; n < 4; ++n)
                    acc[m][n] = __builtin_amdgcn_mfma_f32_16x16x32_bf16(af[m], bfr[n], acc[m][n], 0, 0, 0);
        }
        __syncthreads();
    }

    if (A_F32) {
#pragma unroll
        for (int r = 0; r < 4; ++r) {
            float s = ssq[r];
            s += __shfl_xor(s, 1); s += __shfl_xor(s, 2); s += __shfl_xor(s, 4);
            if ((tid & 7) == 0) rowinv[r * 32 + (tid >> 3)] = 64.f / (sqrtf(s) + 1e-6f);
        }
        __syncthreads();
    }

    const int colbase = n0 + wc * 64 + lrow;
    if (EPI == 0) {
        unsigned short* C = (unsigned short*)Cv;
#pragma unroll
        for (int m = 0; m < 4; ++m) {
            int rloc = wr * 64 + m * 16 + lkh * 4;
#pragma unroll
            for (int r = 0; r < 4; ++r) {
                float riv = rowinv[rloc + r];
#pragma unroll
                for (int n = 0; n < 4; ++n)
                    C[(size_t)(m0 + rloc + r) * ldc + colbase + n * 16] = f2bf(acc[m][n][r] * riv);
            }
        }
    } else {
        float* C = (float*)Cv + (size_t)z * cZ;
#pragma unroll
        for (int m = 0; m < 4; ++m) {
            int row = m0 + wr * 64 + m * 16 + lkh * 4;
#pragma unroll
            for (int r = 0; r < 4; ++r) {
                if ((row + r) >= 16) continue;
#pragma unroll
                for (int n = 0; n < 4; ++n) {
                    int col = colbase + n * 16;
                    if (col < nvalid) C[(size_t)(row + r) * ldc + col] = acc[m][n][r];
                }
            }
        }
    }
}

// ---------- big MFMA GEMM: counted-vmcnt pipeline w/ stage-overlapped MFMA ----------
// BM = FM*32 (FM=8 -> 256, FM=4 -> 128), BN = NH*128 (=256).
// Waves: 2(M) x 4(N); per-wave output = (BM/2) x 64 = FM x 4 frags of 16x16.
// Schedule per K-tile kt (bufs buf[kt&1], 2-deep prefetch; r5 sync invariants):
//   ds_read kk0 frags -> MFMA kk0 -> ds_read kk1 frags
//   lgkmcnt(0); s_barrier                 // all waves' reads of buf[cur] retired
//   stage-A(kt+2) -> MFMA kk1 (1st half) -> stage-B(kt+2) -> MFMA kk1 (2nd half)
//   s_waitcnt vmcnt(LA); s_barrier        // kt+1 landed; kt+2 in flight
// (identical guarantees to r5: stage only after read-retire barrier; every wave's
//  vmcnt(LA) precedes the barrier gating the next tile's reads)
// EPI 1: bf16 elu(x+bias), fused col stats -> ps/pq[(mt*2+wm)][col]
// EPI 2: fp32 x+bias, col<nvalid
template <int FM, int NH, int EPI>
__global__ __launch_bounds__(512, 2) void gemm256(const unsigned short* __restrict__ A,
                                                  const unsigned short* __restrict__ B,
                                                  void* __restrict__ Cv, int K,
                                                  int ntn, int ldc, int nvalid,
                                                  const float* __restrict__ bias,
                                                  float* __restrict__ ps,
                                                  float* __restrict__ pq) {
    constexpr int BM = FM * 32;
    constexpr int MH = BM / 128;
    constexpr int LA = 2 * (MH + NH);   // gloads per thread per K-tile
    __shared__ unsigned short Asl[2][MH][128 * 64];
    __shared__ unsigned short Bsl[2][NH][128 * 64];
    const int tid = threadIdx.x;
    const int lane = tid & 63, wid = tid >> 6;
    const int wm = wid >> 2, wn = wid & 3;
    const int wg = xcd_swz(blockIdx.x, gridDim.x);
    const int m0 = (wg / ntn) * BM, n0 = (wg % ntn) * 256;
    const int lrow = lane & 15, lkh = lane >> 4;
    const int l7 = lane & 7;
    const int ksrc = ((lane & 7) ^ (lane >> 3)) * 8;
    const int mbase = wm * (BM / 2);
    const int mhalf = mbase >> 7;
    const int mloc0 = mbase & 127;
    const int nbase = wn * 64;
    const int nhalf = nbase >> 7;
    const int nloc0 = nbase & 127;

    f32x4 acc[FM][4];
#pragma unroll
    for (int m = 0; m < FM; ++m)
#pragma unroll
        for (int n = 0; n < 4; ++n) acc[m][n] = {0.f, 0.f, 0.f, 0.f};

    const int nkt = K >> 6;

    auto stageA = [&](int kt, int buf) {
#pragma unroll
        for (int hf = 0; hf < MH; ++hf)
#pragma unroll
            for (int j = 0; j < 2; ++j) {
                int rl = wid * 16 + j * 8 + (lane >> 3);
                gload16(A + (size_t)(m0 + hf * 128 + rl) * K + kt * 64 + ksrc,
                        &Asl[buf][hf][(wid * 16 + j * 8) * 64]);
            }
    };
    auto stageB = [&](int kt, int buf) {
#pragma unroll
        for (int hf = 0; hf < NH; ++hf)
#pragma unroll
            for (int j = 0; j < 2; ++j) {
                int rl = wid * 16 + j * 8 + (lane >> 3);
                gload16(B + (size_t)(n0 + hf * 128 + rl) * K + kt * 64 + ksrc,
                        &Bsl[buf][hf][(wid * 16 + j * 8) * 64]);
            }
    };

    // prologue: fill both buffers; wait for buf0 only (buf1 stays in flight)
    stageA(0, 0); stageB(0, 0);
    stageA(1, 1); stageB(1, 1);
    asm volatile("s_waitcnt vmcnt(%0)" :: "i"(LA) : "memory");
    SBAR; __builtin_amdgcn_s_barrier(); SBAR;

    for (int kt = 0; kt < nkt; ++kt) {
        const int cur = kt & 1;
        // ---- kk0 fragment reads ----
        bf16x8 af0[FM], bf0[4];
#pragma unroll
        for (int m = 0; m < FM; ++m) {
            int row = mloc0 + m * 16 + lrow;
            af0[m] = *(const bf16x8*)&Asl[cur][mhalf][row * 64 + ((lkh ^ l7) << 3)];
        }
#pragma unroll
        for (int n = 0; n < 4; ++n) {
            int row = nloc0 + n * 16 + lrow;
            bf0[n] = *(const bf16x8*)&Bsl[cur][nhalf][row * 64 + ((lkh ^ l7) << 3)];
        }
        // ---- kk0 MFMA ----
        __builtin_amdgcn_s_setprio(1);
#pragma unroll
        for (int m = 0; m < FM; ++m)
#pragma unroll
            for (int n = 0; n < 4; ++n)
                acc[m][n] = __builtin_amdgcn_mfma_f32_16x16x32_bf16(af0[m], bf0[n], acc[m][n], 0, 0, 0);
        __builtin_amdgcn_s_setprio(0);
        // ---- kk1 fragment reads ----
        bf16x8 af1[FM], bf1[4];
#pragma unroll
        for (int m = 0; m < FM; ++m) {
            int row = mloc0 + m * 16 + lrow;
            af1[m] = *(const bf16x8*)&Asl[cur][mhalf][row * 64 + (((4 + lkh) ^ l7) << 3)];
        }
#pragma unroll
        for (int n = 0; n < 4; ++n) {
            int row = nloc0 + n * 16 + lrow;
            bf1[n] = *(const bf16x8*)&Bsl[cur][nhalf][row * 64 + (((4 + lkh) ^ l7) << 3)];
        }
        if (kt + 1 < nkt) {
            asm volatile("s_waitcnt lgkmcnt(0)" ::: "memory");
            SBAR; __builtin_amdgcn_s_barrier(); SBAR;
            const bool pf = (kt + 2 < nkt);
            // stage A, MFMA kk1 first half, stage B, MFMA kk1 second half
            if (pf) stageA(kt + 2, cur);
            SBAR;
            __builtin_amdgcn_s_setprio(1);
#pragma unroll
            for (int m = 0; m < FM / 2; ++m)
#pragma unroll
                for (int n = 0; n < 4; ++n)
                    acc[m][n] = __builtin_amdgcn_mfma_f32_16x16x32_bf16(af1[m], bf1[n], acc[m][n], 0, 0, 0);
            __builtin_amdgcn_s_setprio(0);
            if (pf) stageB(kt + 2, cur);
            SBAR;
            __builtin_amdgcn_s_setprio(1);
#pragma unroll
            for (int m = FM / 2; m < FM; ++m)
#pragma unroll
                for (int n = 0; n < 4; ++n)
                    acc[m][n] = __builtin_amdgcn_mfma_f32_16x16x32_bf16(af1[m], bf1[n], acc[m][n], 0, 0, 0);
            __builtin_amdgcn_s_setprio(0);
            if (pf) asm volatile("s_waitcnt vmcnt(%0)" :: "i"(LA) : "memory");
            else    asm volatile("s_waitcnt vmcnt(0)" ::: "memory");
            SBAR; __builtin_amdgcn_s_barrier(); SBAR;
        } else {
            // last tile: no staging
            __builtin_amdgcn_s_setprio(1);
#pragma unroll
            for (int m = 0; m < FM; ++m)
#pragma unroll
                for (int n = 0; n < 4; ++n)
                    acc[m][n] = __builtin_amdgcn_mfma_f32_16x16x32_bf16(af1[m], bf1[n], acc[m][n], 0, 0, 0);
            __builtin_amdgcn_s_setprio(0);
        }
    }

    // ---- epilogue ----
    const int colbase = n0 + nbase + lrow;
    if (EPI == 1) {
        unsigned short* C = (unsigned short*)Cv;
        float bv[4], sN[4] = {0.f, 0.f, 0.f, 0.f}, qN[4] = {0.f, 0.f, 0.f, 0.f};
#pragma unroll
        for (int n = 0; n < 4; ++n) bv[n] = bias[colbase + n * 16];
#pragma unroll
        for (int m = 0; m < FM; ++m) {
            int row = m0 + mbase + m * 16 + lkh * 4;
#pragma unroll
            for (int r = 0; r < 4; ++r)
#pragma unroll
                for (int n = 0; n < 4; ++n) {
                    float v = acc[m][n][r] + bv[n];
                    v = v > 0.f ? v : expm1f(v);
                    sN[n] += v;
                    qN[n] = fmaf(v, v, qN[n]);
                    C[(size_t)(row + r) * ldc + colbase + n * 16] = f2bf(v);
                }
        }
#pragma unroll
        for (int n = 0; n < 4; ++n) {
            sN[n] += __shfl_xor(sN[n], 16); sN[n] += __shfl_xor(sN[n], 32);
            qN[n] += __shfl_xor(qN[n], 16); qN[n] += __shfl_xor(qN[n], 32);
        }
        if (lane < 16) {
            int mt = wg / ntn;
#pragma unroll
            for (int n = 0; n < 4; ++n) {
                ps[(size_t)(mt * 2 + wm) * ldc + colbase + n * 16] = sN[n];
                pq[(size_t)(mt * 2 + wm) * ldc + colbase + n * 16] = qN[n];
            }
        }
    } else {
        float* C = (float*)Cv;
        float bv[4];
#pragma unroll
        for (int n = 0; n < 4; ++n) bv[n] = bias[colbase + n * 16];
#pragma unroll
        for (int m = 0; m < FM; ++m) {
            int row = m0 + mbase + m * 16 + lkh * 4;
#pragma unroll
            for (int r = 0; r < 4; ++r)
#pragma unroll
                for (int n = 0; n < 4; ++n) {
                    int col = colbase + n * 16;
                    if (col < nvalid) C[(size_t)(row + r) * ldc + col] = acc[m][n][r] + bv[n];
                }
        }
    }
}

// ---------------- launch ----------------
extern "C" void kernel_launch(void* const* d_in, const int* in_sizes, int n_in,
                              void* d_out, int out_size, void* d_ws, size_t ws_size,
                              hipStream_t stream) {
    const float* img_f    = (const float*)d_in[0];   // (8192,8,512)
    const float* tex_f    = (const float*)d_in[1];   // (8,1000,512)
    const float* fake_cls = (const float*)d_in[2];   // (8,16,512)
    const float* fc_w     = (const float*)d_in[3];   // (512,512)
    const float* bn1_g    = (const float*)d_in[5];   // (1024)
    const float* bn1_b    = (const float*)d_in[6];
    const float* w1       = (const float*)d_in[7];   // (2048,1024)
    const float* b1       = (const float*)d_in[8];
    const float* bn2_g    = (const float*)d_in[9];   // (2048)
    const float* bn2_b    = (const float*)d_in[10];
    const float* w2       = (const float*)d_in[11];  // (1000,2048)
    const float* b2       = (const float*)d_in[12];
    float* out = (float*)d_out;

    char* w = (char*)d_ws;   // byte offsets; total ~73.3 MB
    unsigned short* texn = (unsigned short*)(w);             // 8,388,608 (8000 rows + pad)
    unsigned short* g_bf = (unsigned short*)(w + 8388608);   //   262,144 (128 rows + pad)
    float*          logit= (float*)(w + 8650752);            //   524,288 (128x1000)
    float*          part = (float*)(w + 9175040);            // 4,194,304 (16x8x16x512)
    unsigned short* texa = (unsigned short*)(w + 13369344);  //   131,072
    unsigned short* cp   = (unsigned short*)(w + 13500416);  // 16,777,216
    unsigned short* w1a  = (unsigned short*)(w + 30277632);  //  4,194,304
    float*          b1p  = (float*)(w + 34471936);           //      8,192
    float*          a1   = (float*)(w + 34480128);
    float*          c1   = (float*)(w + 34484224);
    float*          ps   = (float*)(w + 34488320);           //    524,288
    float*          pq   = (float*)(w + 35012608);           //    524,288
    unsigned short* h    = (unsigned short*)(w + 35536896);  // 33,554,432
    unsigned short* w2a  = (unsigned short*)(w + 69091328);  //  4,194,304
    float*          b2p  = (float*)(w + 73285632);
    float*          a2   = (float*)(w + 73289728);
    float*          c2   = (float*)(w + 73297920);

    // ---- attention path ----
    k_prep<<<8128, 256, 0, stream>>>(tex_f, texn, fake_cls, fc_w, g_bf);
    gemm_mfma<3, false><<<dim3(8, 8), 256, 0, stream>>>(
        g_bf, texn, logit, 512, 8, 1000, 1000, 16 * 512, 1000 * 512, 16 * 1000);
    k_wsum_sm<<<dim3(16, 8), 256, 0, stream>>>(logit, texn, part);
    k_texa_red<<<128, 256, 0, stream>>>(part, texa);

    // ---- cp' = (img @ texa^T)*inv -> bf16, permuted cols (65536 x 128) ----
    gemm_mfma<0, true><<<dim3(512, 1), 256, 0, stream>>>(
        img_f, texa, cp, 512, 1, 128, 128, 0, 0, 0);

    // ---- BN1 -> fold into w1 (column permutation) ----
    k_colstat_bf<<<dim3(4, 64), 256, 0, stream>>>(cp, ps, pq, 1024);
    k_bnfin<true><<<4, 256, 0, stream>>>(ps, pq, bn1_g, bn1_b, a1, c1, 1024);
    k_foldw_bf<true><<<2048, 256, 0, stream>>>(w1, b1, a1, c1, w1a, b1p, 1024, 2048);

    // ---- h = elu(cp' @ w1a^T + b1p) -> bf16, col-stats fused (256x256 tiles) ----
    gemm256<8, 2, 1><<<dim3(256), 512, 0, stream>>>(
        cp, w1a, h, 1024, 8, 2048, 2048, b1p, ps, pq);

    // ---- BN2 -> fold into w2 (pad rows to 1024) ----
    k_bnfin<false><<<8, 256, 0, stream>>>(ps, pq, bn2_g, bn2_b, a2, c2, 2048);
    k_foldw_bf<false><<<1024, 256, 0, stream>>>(w2, b2, a2, c2, w2a, b2p, 2048, 1000);

    // ---- out = h @ w2a^T + b2p -> fp32 (128x256 tiles) ----
    gemm256<4, 2, 2><<<dim3(256), 512, 0, stream>>>(
        h, w2a, out, 2048, 4, 1000, 1000, b2p, nullptr, nullptr);
}

// Round 9
// 295.385 us; speedup vs baseline: 1.6521x; 1.6521x over previous
//
#include <hip/hip_runtime.h>
#include <math.h>

// B=8192, X=8, C=512, P=8, Y=1000, FAKE=16, F=2048, CLS=1000, IN_DIM=1024, SF=64
//
// Pipeline (11 launches; r5 structure with bnfin1 fused into colstat):
//  k_prep:   texn = rownorm(tex_f)->bf16  |  g_bf = fake_cls @ fc_w ->bf16 | cnt=0
//  logits[p] = g_bf[p] @ texn[p]^T            [MFMA128 EPI3, z=p]
//  k_wsum_sm: softmax(logits) fused, partial texa sums
//  k_texa_red: reduce -> texa bf16
//  cp' = (img @ texa^T) * inv_row             [MFMA128 EPI0, A fp32 reg-staged,
//                                              row-norm inline, out bf16, permuted cols]
//  colstat(cp) + last-block bnfin1 -> a1,c1
//  foldw1 (perm) -> w1a bf16, b1p
//  h = elu(cp' @ w1a^T + b1p)                 [gemm256 FM=8, r5 pipeline VERBATIM,
//                                              col-stats fused -> ps/pq (64 rows)]
//  bnfin2 -> foldw2 (pad 1024)                [bf16 weights]
//  out = h @ w2a^T + b2p                      [gemm256 FM=4, fp32]

typedef __attribute__((ext_vector_type(8))) short bf16x8;
typedef __attribute__((ext_vector_type(4))) float f32x4;

__device__ __forceinline__ float waveSum(float v) {
#pragma unroll
    for (int o = 32; o > 0; o >>= 1) v += __shfl_xor(v, o);
    return v;
}
__device__ __forceinline__ float waveMax(float v) {
#pragma unroll
    for (int o = 32; o > 0; o >>= 1) v = fmaxf(v, __shfl_xor(v, o));
    return v;
}
__device__ __forceinline__ unsigned short f2bf(float x) {
    union { float f; unsigned u; } v; v.f = x;
    unsigned r = v.u + 0x7FFFu + ((v.u >> 16) & 1u);
    return (unsigned short)(r >> 16);
}
__device__ __forceinline__ float bf2f(unsigned short h) {
    union { unsigned u; float f; } v; v.u = ((unsigned)h) << 16; return v.f;
}
__device__ __forceinline__ void gload16(const void* g, const void* l) {
    __builtin_amdgcn_global_load_lds((const __attribute__((address_space(1))) void*)g,
                                     (__attribute__((address_space(3))) void*)l, 16, 0, 0);
}
__device__ __forceinline__ int xcd_swz(int d, int n) {
    int q = n >> 3;                     // all gemm grids are %8==0
    return (d & 7) * q + (d >> 3);
}
#define SBAR __builtin_amdgcn_sched_barrier(0)

// ---------- fused: rownorm(tex_f)->texn bf16 (blocks 0..7999), g_bf (8000..8127) ----------
__global__ __launch_bounds__(256) void k_prep(const float* __restrict__ tex_f,
                                              unsigned short* __restrict__ texn,
                                              const float* __restrict__ fake_cls,
                                              const float* __restrict__ fc_w,
                                              unsigned short* __restrict__ g_bf,
                                              unsigned* __restrict__ cnt) {
    __shared__ float sred[4];
    __shared__ float fcls[512];
    int bid = blockIdx.x, t = threadIdx.x;
    if (bid == 0 && t == 0) *cnt = 0;   // reset colstat's last-block counter (stream-ordered)
    if (bid < 8000) {
        const float* r = tex_f + (size_t)bid * 512;
        float2 v = *(const float2*)(r + t * 2);
        float ss = v.x * v.x + v.y * v.y;
        ss = waveSum(ss);
        if ((t & 63) == 0) sred[t >> 6] = ss;
        __syncthreads();
        float tot = sred[0] + sred[1] + sred[2] + sred[3];
        float sc = 64.f / (sqrtf(tot) + 1e-6f);
        unsigned u = (unsigned)f2bf(v.x * sc) | ((unsigned)f2bf(v.y * sc) << 16);
        *(unsigned*)(texn + (size_t)bid * 512 + t * 2) = u;
    } else {
        int row = bid - 8000;
        fcls[t]       = fake_cls[row * 512 + t];
        fcls[t + 256] = fake_cls[row * 512 + t + 256];
        __syncthreads();
        float a0 = 0.f, a1 = 0.f;
        for (int d = 0; d < 512; ++d) {
            float fv = fcls[d];
            a0 = fmaf(fv, fc_w[d * 512 + t], a0);
            a1 = fmaf(fv, fc_w[d * 512 + t + 256], a1);
        }
        g_bf[row * 512 + t]       = f2bf(a0);
        g_bf[row * 512 + t + 256] = f2bf(a1);
    }
}

// ---------- wsum with fused softmax: block (yt 0..15, p 0..7) ----------
__global__ __launch_bounds__(256) void k_wsum_sm(const float* __restrict__ logit,
                                                 const unsigned short* __restrict__ texn,
                                                 float* __restrict__ part) {
    int yt = blockIdx.x, p = blockIdx.y, t = threadIdx.x;
    int lane = t & 63, w = t >> 6;
    __shared__ float wl[16][63];
    __shared__ float ms[16], iss[16];
    const int y0 = yt * 63;
    const int ylen = min(63, 1000 - y0);
#pragma unroll
    for (int rr = 0; rr < 4; ++rr) {
        int x = w * 4 + rr;
        const float* lr = logit + ((size_t)p * 16 + x) * 1000;
        float m = -3.0e38f;
        for (int y = lane; y < 1000; y += 64) m = fmaxf(m, lr[y]);
        m = waveMax(m);
        float s = 0.f;
        for (int y = lane; y < 1000; y += 64) s += expf(lr[y] - m);
        s = waveSum(s);
        if (lane == 0) { ms[x] = m; iss[x] = 1.f / s; }
    }
    __syncthreads();
    for (int idx = t; idx < 16 * ylen; idx += 256) {
        int x = idx / ylen, y = idx % ylen;
        wl[x][y] = expf(logit[((size_t)p * 16 + x) * 1000 + y0 + y] - ms[x]) * iss[x];
    }
    __syncthreads();
    int c0 = t * 2;
    const unsigned short* tp = texn + ((size_t)p * 1000 + y0) * 512 + c0;
    float a0[16], a1[16];
#pragma unroll
    for (int x = 0; x < 16; ++x) { a0[x] = 0.f; a1[x] = 0.f; }
    for (int y = 0; y < ylen; ++y) {
        unsigned u = *(const unsigned*)(tp + (size_t)y * 512);
        float lo = bf2f((unsigned short)(u & 0xffff));
        float hi = bf2f((unsigned short)(u >> 16));
#pragma unroll
        for (int x = 0; x < 16; ++x) {
            float ww = wl[x][y];
            a0[x] = fmaf(ww, lo, a0[x]);
            a1[x] = fmaf(ww, hi, a1[x]);
        }
    }
#pragma unroll
    for (int x = 0; x < 16; ++x) {
        float* dst = part + ((size_t)((yt * 8 + p) * 16 + x)) * 512 + c0;
        dst[0] = a0[x];
        dst[1] = a1[x];
    }
}

// ---------- reduce 16 y-partials -> texa bf16 ----------
__global__ __launch_bounds__(256) void k_texa_red(const float* __restrict__ part,
                                                  unsigned short* __restrict__ texa) {
    int row = blockIdx.x, t = threadIdx.x;      // row = p*16 + x
    int p = row >> 4, x = row & 15;
    int c = t * 2;
    float s0 = 0.f, s1 = 0.f;
#pragma unroll
    for (int yt = 0; yt < 16; ++yt) {
        const float* src = part + ((size_t)((yt * 8 + p) * 16 + x)) * 512 + c;
        s0 += src[0];
        s1 += src[1];
    }
    unsigned u = (unsigned)f2bf(s0) | ((unsigned)f2bf(s1) << 16);
    *(unsigned*)(texa + (size_t)row * 512 + c) = u;
}

// ---------- column stats over cp (bf16) + last-block bnfin1 (PERM map) ----------
__global__ __launch_bounds__(256) void k_colstat_bn1(const unsigned short* __restrict__ src,
                                                     float* __restrict__ ps,
                                                     float* __restrict__ pq,
                                                     const float* __restrict__ gam,
                                                     const float* __restrict__ bet,
                                                     float* __restrict__ a1,
                                                     float* __restrict__ c1,
                                                     unsigned* __restrict__ cnt) {
    const int ncols = 1024;
    int col = blockIdx.x * 256 + threadIdx.x;
    int r0 = blockIdx.y * 128;
    const unsigned short* p = src + (size_t)r0 * ncols + col;
    float s = 0.f, q = 0.f;
    for (int r = 0; r < 128; ++r) {
        float v = bf2f(p[(size_t)r * ncols]);
        s += v;
        q = fmaf(v, v, q);
    }
    ps[(size_t)blockIdx.y * ncols + col] = s;
    pq[(size_t)blockIdx.y * ncols + col] = q;
    // last-block-done: reduce + bnfin (writer fence -> atomic -> reader fence)
    __shared__ bool amLast;
    __threadfence();
    __syncthreads();
    if (threadIdx.x == 0)
        amLast = (atomicAdd(cnt, 1u) == gridDim.x * gridDim.y - 1);
    __syncthreads();
    if (amLast) {
        __threadfence();
        for (int c = threadIdx.x; c < 1024; c += 256) {
            float S = 0.f, Q = 0.f;
            for (int i = 0; i < 64; ++i) {
                S += ps[(size_t)i * ncols + c];
                Q += pq[(size_t)i * ncols + c];
            }
            float mean = S * (1.f / 8192.f);
            float var = Q * (1.f / 8192.f) - mean * mean;
            int x = c >> 7, jj = c & 127, pp = jj >> 4, d = jj & 15;
            int j = (pp << 7) + (x << 4) + d;
            float av = gam[j] * rsqrtf(var + 1e-5f);
            a1[c] = av;
            c1[c] = bet[j] - mean * av;
        }
    }
}

// ---------- finalize BN scale/shift (BN2 only) ----------
__global__ __launch_bounds__(256) void k_bnfin2(const float* __restrict__ ps,
                                                const float* __restrict__ pq,
                                                const float* __restrict__ gam,
                                                const float* __restrict__ bet,
                                                float* __restrict__ a, float* __restrict__ c,
                                                int ncols) {
    int col = blockIdx.x * 256 + threadIdx.x;
    float S = 0.f, Q = 0.f;
    for (int i = 0; i < 64; ++i) {
        S += ps[(size_t)i * ncols + col];
        Q += pq[(size_t)i * ncols + col];
    }
    float mean = S * (1.f / 8192.f);
    float var = Q * (1.f / 8192.f) - mean * mean;
    float av = gam[col] * rsqrtf(var + 1e-5f);
    a[col] = av;
    c[col] = bet[col] - mean * av;
}

// ---------- fold BN into weights -> bf16 ----------
template <bool PERM>
__global__ __launch_bounds__(256) void k_foldw_bf(const float* __restrict__ W,
                                                  const float* __restrict__ bin,
                                                  const float* __restrict__ a,
                                                  const float* __restrict__ c,
                                                  unsigned short* __restrict__ Wout,
                                                  float* __restrict__ bout,
                                                  int Kdim, int nvalid) {
    int f = blockIdx.x, t = threadIdx.x;
    unsigned short* wo = Wout + (size_t)f * Kdim;
    if (f >= nvalid) {
        for (int col = t; col < Kdim; col += 256) wo[col] = 0;
        if (t == 0) bout[f] = 0.f;
        return;
    }
    const float* wr = W + (size_t)f * Kdim;
    float partial = 0.f;
    for (int col = t; col < Kdim; col += 256) {
        int j = col;
        if (PERM) {
            int x = col >> 7, jj = col & 127, pp = jj >> 4, d = jj & 15;
            j = (pp << 7) + (x << 4) + d;
        }
        float wv = wr[j];
        wo[col] = f2bf(wv * a[col]);
        partial = fmaf(wv, c[col], partial);
    }
    partial = waveSum(partial);
    __shared__ float sred[4];
    if ((t & 63) == 0) sred[t >> 6] = partial;
    __syncthreads();
    if (t == 0) bout[f] = bin[f] + sred[0] + sred[1] + sred[2] + sred[3];
}

// ---------- small MFMA GEMM (128x128 tile, 4 waves) for cp & logits ----------
// EPI 0 (A_F32): bf16 store * rowinv computed inline from A's fp32 rows (cp)
// EPI 3: fp32 store, col<nvalid, row<16 (logits, batched over z=p)
template <int EPI, bool A_F32>
__global__ __launch_bounds__(256) void gemm_mfma(const void* __restrict__ Av,
                                                 const unsigned short* __restrict__ Bv,
                                                 void* __restrict__ Cv, int K,
                                                 int ntn, int ldc, int nvalid,
                                                 int aZ, int bZ, int cZ) {
    __shared__ unsigned short Asl[128 * 64];
    __shared__ unsigned short Bsl[128 * 64];
    __shared__ float rowinv[128];
    const int tid = threadIdx.x;
    const int lane = tid & 63, wid = tid >> 6;
    const int wr = wid >> 1, wc = wid & 1;
    const int wg = xcd_swz(blockIdx.x, gridDim.x);
    const int m0 = (wg / ntn) * 128, n0 = (wg % ntn) * 128;
    const int z = blockIdx.y;

    const float* Af = (const float*)Av;
    const unsigned short* Ab = (const unsigned short*)Av + (size_t)z * aZ;
    const unsigned short* B = Bv + (size_t)z * bZ;

    f32x4 acc[4][4];
#pragma unroll
    for (int i = 0; i < 4; ++i)
#pragma unroll
        for (int j = 0; j < 4; ++j) acc[i][j] = {0.f, 0.f, 0.f, 0.f};

    const int swz = ((lane & 7) ^ (lane >> 3)) * 8;
    const int lrow = lane & 15, lkh = lane >> 4;
    float ssq[4] = {0.f, 0.f, 0.f, 0.f};

    for (int k0 = 0; k0 < K; k0 += 64) {
        if (A_F32) {
#pragma unroll
            for (int r = 0; r < 4; ++r) {
                int row = r * 32 + (tid >> 3);
                int kk = (tid & 7) * 8;
                const float* src = Af + (size_t)(m0 + row) * K + k0 + kk;
                float4 p0 = *(const float4*)src;
                float4 p1 = *(const float4*)(src + 4);
                ssq[r] += p0.x*p0.x + p0.y*p0.y + p0.z*p0.z + p0.w*p0.w
                        + p1.x*p1.x + p1.y*p1.y + p1.z*p1.z + p1.w*p1.w;
                bf16x8 v;
                v[0] = (short)f2bf(p0.x); v[1] = (short)f2bf(p0.y);
                v[2] = (short)f2bf(p0.z); v[3] = (short)f2bf(p0.w);
                v[4] = (short)f2bf(p1.x); v[5] = (short)f2bf(p1.y);
                v[6] = (short)f2bf(p1.z); v[7] = (short)f2bf(p1.w);
                *(bf16x8*)&Asl[row * 64 + (kk ^ ((row & 7) << 3))] = v;
            }
        } else {
#pragma unroll
            for (int r = 0; r < 4; ++r) {
                int row = r * 32 + wid * 8 + (lane >> 3);
                gload16(Ab + (size_t)(m0 + row) * K + k0 + swz,
                        Asl + r * 2048 + wid * 512);
            }
        }
#pragma unroll
        for (int r = 0; r < 4; ++r) {
            int row = r * 32 + wid * 8 + (lane >> 3);
            gload16(B + (size_t)(n0 + row) * K + k0 + swz,
                    Bsl + r * 2048 + wid * 512);
        }
        __syncthreads();
#pragma unroll
        for (int kk = 0; kk < 2; ++kk) {
            bf16x8 af[4], bfr[4];
#pragma unroll
            for (int m = 0; m < 4; ++m) {
                int row = wr * 64 + m * 16 + lrow;
                af[m] = *(const bf16x8*)&Asl[row * 64 + ((kk * 32 + lkh * 8) ^ ((row & 7) << 3))];
            }
#pragma unroll
            for (int n = 0; n < 4; ++n) {
                int row = wc * 64 + n * 16 + lrow;
                bfr[n] = *(const bf16x8*)&Bsl[row * 64 + ((kk * 32 + lkh * 8) ^ ((row & 7) << 3))];
            }
#pragma unroll
            for (int m = 0; m < 4; ++m)
#pragma unroll
                for (int n = 0; n < 4; ++n)
                    acc[m][n] = __builtin_amdgcn_mfma_f32_16x16x32_bf16(af[m], bfr[n], acc[m][n], 0, 0, 0);
        }
        __syncthreads();
    }

    if (A_F32) {
#pragma unroll
        for (int r = 0; r < 4; ++r) {
            float s = ssq[r];
            s += __shfl_xor(s, 1); s += __shfl_xor(s, 2); s += __shfl_xor(s, 4);
            if ((tid & 7) == 0) rowinv[r * 32 + (tid >> 3)] = 64.f / (sqrtf(s) + 1e-6f);
        }
        __syncthreads();
    }

    const int colbase = n0 + wc * 64 + lrow;
    if (EPI == 0) {
        unsigned short* C = (unsigned short*)Cv;
#pragma unroll
        for (int m = 0; m < 4; ++m) {
            int rloc = wr * 64 + m * 16 + lkh * 4;
#pragma unroll
            for (int r = 0; r < 4; ++r) {
                float riv = rowinv[rloc + r];
#pragma unroll
                for (int n = 0; n < 4; ++n)
                    C[(size_t)(m0 + rloc + r) * ldc + colbase + n * 16] = f2bf(acc[m][n][r] * riv);
            }
        }
    } else {
        float* C = (float*)Cv + (size_t)z * cZ;
#pragma unroll
        for (int m = 0; m < 4; ++m) {
            int row = m0 + wr * 64 + m * 16 + lkh * 4;
#pragma unroll
            for (int r = 0; r < 4; ++r) {
                if ((row + r) >= 16) continue;
#pragma unroll
                for (int n = 0; n < 4; ++n) {
                    int col = colbase + n * 16;
                    if (col < nvalid) C[(size_t)(row + r) * ldc + col] = acc[m][n][r];
                }
            }
        }
    }
}

// ---------- big MFMA GEMM: r5-verified counted-vmcnt pipeline, 8 waves (VERBATIM r5) ----------
// BM = FM*32 (FM=8 -> 256, FM=4 -> 128), BN = NH*128 (=256).
// Waves: 2(M) x 4(N); per-wave output = (BM/2) x 64 = FM x 4 frags of 16x16.
// Schedule per K-tile kt (buffers buf[kt&1], 2-deep prefetch):
//   ds_read kk0 frags -> MFMA kk0 -> ds_read kk1 frags
//   lgkmcnt(0); s_barrier            // all waves' reads of buf[cur] retired
//   stage(kt+2 -> buf[cur]); s_waitcnt vmcnt(LA)   // kt+1 landed; kt+2 in flight
//   s_barrier                        // buf[cur^1] globally ready
//   MFMA kk1 (register-only; overlaps kt+2 flight & next iter's reads)
// EPI 1: bf16 elu(x+bias), col stats -> ps/pq[(mt*2+wm)][col]
// EPI 2: fp32 x+bias, col<nvalid
template <int FM, int NH, int EPI>
__global__ __launch_bounds__(512, 2) void gemm256(const unsigned short* __restrict__ A,
                                                  const unsigned short* __restrict__ B,
                                                  void* __restrict__ Cv, int K,
                                                  int ntn, int ldc, int nvalid,
                                                  const float* __restrict__ bias,
                                                  float* __restrict__ ps,
                                                  float* __restrict__ pq) {
    constexpr int BM = FM * 32;
    constexpr int MH = BM / 128;
    constexpr int LA = 2 * (MH + NH);   // gloads per thread per K-tile
    __shared__ unsigned short Asl[2][MH][128 * 64];
    __shared__ unsigned short Bsl[2][NH][128 * 64];
    const int tid = threadIdx.x;
    const int lane = tid & 63, wid = tid >> 6;
    const int wm = wid >> 2, wn = wid & 3;
    const int wg = xcd_swz(blockIdx.x, gridDim.x);
    const int m0 = (wg / ntn) * BM, n0 = (wg % ntn) * 256;
    const int lrow = lane & 15, lkh = lane >> 4;
    const int l7 = lane & 7;
    const int ksrc = ((lane & 7) ^ (lane >> 3)) * 8;
    const int mbase = wm * (BM / 2);
    const int mhalf = mbase >> 7;
    const int mloc0 = mbase & 127;
    const int nbase = wn * 64;
    const int nhalf = nbase >> 7;
    const int nloc0 = nbase & 127;

    f32x4 acc[FM][4];
#pragma unroll
    for (int m = 0; m < FM; ++m)
#pragma unroll
        for (int n = 0; n < 4; ++n) acc[m][n] = {0.f, 0.f, 0.f, 0.f};

    const int nkt = K >> 6;

    auto stage = [&](int kt, int buf) {
#pragma unroll
        for (int hf = 0; hf < MH; ++hf)
#pragma unroll
            for (int j = 0; j < 2; ++j) {
                int rl = wid * 16 + j * 8 + (lane >> 3);
                gload16(A + (size_t)(m0 + hf * 128 + rl) * K + kt * 64 + ksrc,
                        &Asl[buf][hf][(wid * 16 + j * 8) * 64]);
            }
#pragma unroll
        for (int hf = 0; hf < NH; ++hf)
#pragma unroll
            for (int j = 0; j < 2; ++j) {
                int rl = wid * 16 + j * 8 + (lane >> 3);
                gload16(B + (size_t)(n0 + hf * 128 + rl) * K + kt * 64 + ksrc,
                        &Bsl[buf][hf][(wid * 16 + j * 8) * 64]);
            }
    };

    // prologue: fill both buffers; wait for buf0 only (buf1 stays in flight)
    stage(0, 0);
    stage(1, 1);
    if constexpr (LA == 8) asm volatile("s_waitcnt vmcnt(8)" ::: "memory");
    else asm volatile("s_waitcnt vmcnt(6)" ::: "memory");
    SBAR; __builtin_amdgcn_s_barrier(); SBAR;

    for (int kt = 0; kt < nkt; ++kt) {
        const int cur = kt & 1;
        // ---- kk0 fragment reads ----
        bf16x8 af0[FM], bf0[4];
#pragma unroll
        for (int m = 0; m < FM; ++m) {
            int row = mloc0 + m * 16 + lrow;
            af0[m] = *(const bf16x8*)&Asl[cur][mhalf][row * 64 + ((lkh ^ l7) << 3)];
        }
#pragma unroll
        for (int n = 0; n < 4; ++n) {
            int row = nloc0 + n * 16 + lrow;
            bf0[n] = *(const bf16x8*)&Bsl[cur][nhalf][row * 64 + ((lkh ^ l7) << 3)];
        }
        // ---- kk0 MFMA ----
        __builtin_amdgcn_s_setprio(1);
#pragma unroll
        for (int m = 0; m < FM; ++m)
#pragma unroll
            for (int n = 0; n < 4; ++n)
                acc[m][n] = __builtin_amdgcn_mfma_f32_16x16x32_bf16(af0[m], bf0[n], acc[m][n], 0, 0, 0);
        __builtin_amdgcn_s_setprio(0);
        // ---- kk1 fragment reads ----
        bf16x8 af1[FM], bf1[4];
#pragma unroll
        for (int m = 0; m < FM; ++m) {
            int row = mloc0 + m * 16 + lrow;
            af1[m] = *(const bf16x8*)&Asl[cur][mhalf][row * 64 + (((4 + lkh) ^ l7) << 3)];
        }
#pragma unroll
        for (int n = 0; n < 4; ++n) {
            int row = nloc0 + n * 16 + lrow;
            bf1[n] = *(const bf16x8*)&Bsl[cur][nhalf][row * 64 + (((4 + lkh) ^ l7) << 3)];
        }
        if (kt + 1 < nkt) {
            asm volatile("s_waitcnt lgkmcnt(0)" ::: "memory");
            SBAR; __builtin_amdgcn_s_barrier(); SBAR;
            if (kt + 2 < nkt) {
                stage(kt + 2, cur);
                if constexpr (LA == 8) asm volatile("s_waitcnt vmcnt(8)" ::: "memory");
                else asm volatile("s_waitcnt vmcnt(6)" ::: "memory");
            } else {
                asm volatile("s_waitcnt vmcnt(0)" ::: "memory");
            }
            SBAR; __builtin_amdgcn_s_barrier(); SBAR;
        }
        // ---- kk1 MFMA (register-only; overlaps kt+2 flight & next reads) ----
        __builtin_amdgcn_s_setprio(1);
#pragma unroll
        for (int m = 0; m < FM; ++m)
#pragma unroll
            for (int n = 0; n < 4; ++n)
                acc[m][n] = __builtin_amdgcn_mfma_f32_16x16x32_bf16(af1[m], bf1[n], acc[m][n], 0, 0, 0);
        __builtin_amdgcn_s_setprio(0);
    }

    // ---- epilogue ----
    const int colbase = n0 + nbase + lrow;
    if (EPI == 1) {
        unsigned short* C = (unsigned short*)Cv;
        float bv[4], sN[4] = {0.f, 0.f, 0.f, 0.f}, qN[4] = {0.f, 0.f, 0.f, 0.f};
#pragma unroll
        for (int n = 0; n < 4; ++n) bv[n] = bias[colbase + n * 16];
#pragma unroll
        for (int m = 0; m < FM; ++m) {
            int row = m0 + mbase + m * 16 + lkh * 4;
#pragma unroll
            for (int r = 0; r < 4; ++r)
#pragma unroll
                for (int n = 0; n < 4; ++n) {
                    float v = acc[m][n][r] + bv[n];
                    v = v > 0.f ? v : expm1f(v);
                    sN[n] += v;
                    qN[n] = fmaf(v, v, qN[n]);
                    C[(size_t)(row + r) * ldc + colbase + n * 16] = f2bf(v);
                }
        }
#pragma unroll
        for (int n = 0; n < 4; ++n) {
            sN[n] += __shfl_xor(sN[n], 16); sN[n] += __shfl_xor(sN[n], 32);
            qN[n] += __shfl_xor(qN[n], 16); qN[n] += __shfl_xor(qN[n], 32);
        }
        if (lane < 16) {
            int mt = wg / ntn;
#pragma unroll
            for (int n = 0; n < 4; ++n) {
                ps[(size_t)(mt * 2 + wm) * ldc + colbase + n * 16] = sN[n];
                pq[(size_t)(mt * 2 + wm) * ldc + colbase + n * 16] = qN[n];
            }
        }
    } else {
        float* C = (float*)Cv;
        float bv[4];
#pragma unroll
        for (int n = 0; n < 4; ++n) bv[n] = bias[colbase + n * 16];
#pragma unroll
        for (int m = 0; m < FM; ++m) {
            int row = m0 + mbase + m * 16 + lkh * 4;
#pragma unroll
            for (int r = 0; r < 4; ++r)
#pragma unroll
                for (int n = 0; n < 4; ++n) {
                    int col = colbase + n * 16;
                    if (col < nvalid) C[(size_t)(row + r) * ldc + col] = acc[m][n][r] + bv[n];
                }
        }
    }
}

// ---------------- launch ----------------
extern "C" void kernel_launch(void* const* d_in, const int* in_sizes, int n_in,
                              void* d_out, int out_size, void* d_ws, size_t ws_size,
                              hipStream_t stream) {
    const float* img_f    = (const float*)d_in[0];   // (8192,8,512)
    const float* tex_f    = (const float*)d_in[1];   // (8,1000,512)
    const float* fake_cls = (const float*)d_in[2];   // (8,16,512)
    const float* fc_w     = (const float*)d_in[3];   // (512,512)
    const float* bn1_g    = (const float*)d_in[5];   // (1024)
    const float* bn1_b    = (const float*)d_in[6];
    const float* w1       = (const float*)d_in[7];   // (2048,1024)
    const float* b1       = (const float*)d_in[8];
    const float* bn2_g    = (const float*)d_in[9];   // (2048)
    const float* bn2_b    = (const float*)d_in[10];
    const float* w2       = (const float*)d_in[11];  // (1000,2048)
    const float* b2       = (const float*)d_in[12];
    float* out = (float*)d_out;

    char* w = (char*)d_ws;   // byte offsets; total ~73.3 MB
    unsigned short* texn = (unsigned short*)(w);             // 8,388,608 (8000 rows + pad)
    unsigned short* g_bf = (unsigned short*)(w + 8388608);   //   262,144 (128 rows + pad)
    float*          logit= (float*)(w + 8650752);            //   524,288 (128x1000)
    float*          part = (float*)(w + 9175040);            // 4,194,304 (16x8x16x512)
    unsigned short* texa = (unsigned short*)(w + 13369344);  //   131,072
    unsigned short* cp   = (unsigned short*)(w + 13500416);  // 16,777,216
    unsigned short* w1a  = (unsigned short*)(w + 30277632);  //  4,194,304
    float*          b1p  = (float*)(w + 34471936);           //      8,192
    float*          a1   = (float*)(w + 34480128);
    float*          c1   = (float*)(w + 34484224);
    float*          ps   = (float*)(w + 34488320);           //    524,288
    float*          pq   = (float*)(w + 35012608);           //    524,288
    unsigned short* h    = (unsigned short*)(w + 35536896);  // 33,554,432
    unsigned short* w2a  = (unsigned short*)(w + 69091328);  //  4,194,304
    float*          b2p  = (float*)(w + 73285632);
    float*          a2   = (float*)(w + 73289728);
    float*          c2   = (float*)(w + 73297920);
    unsigned*       cnt  = (unsigned*)(w + 73306112);        //          4

    // ---- attention path ----
    k_prep<<<8128, 256, 0, stream>>>(tex_f, texn, fake_cls, fc_w, g_bf, cnt);
    gemm_mfma<3, false><<<dim3(8, 8), 256, 0, stream>>>(
        g_bf, texn, logit, 512, 8, 1000, 1000, 16 * 512, 1000 * 512, 16 * 1000);
    k_wsum_sm<<<dim3(16, 8), 256, 0, stream>>>(logit, texn, part);
    k_texa_red<<<128, 256, 0, stream>>>(part, texa);

    // ---- cp' = (img @ texa^T)*inv -> bf16, permuted cols (65536 x 128) ----
    gemm_mfma<0, true><<<dim3(512, 1), 256, 0, stream>>>(
        img_f, texa, cp, 512, 1, 128, 128, 0, 0, 0);

    // ---- BN1 stats + fused bnfin1 -> fold into w1 (column permutation) ----
    k_colstat_bn1<<<dim3(4, 64), 256, 0, stream>>>(cp, ps, pq, bn1_g, bn1_b, a1, c1, cnt);
    k_foldw_bf<true><<<2048, 256, 0, stream>>>(w1, b1, a1, c1, w1a, b1p, 1024, 2048);

    // ---- h = elu(cp' @ w1a^T + b1p) -> bf16, col-stats fused (256x256 tiles) ----
    gemm256<8, 2, 1><<<dim3(256), 512, 0, stream>>>(
        cp, w1a, h, 1024, 8, 2048, 2048, b1p, ps, pq);

    // ---- BN2 -> fold into w2 (pad rows to 1024) ----
    k_bnfin2<<<8, 256, 0, stream>>>(ps, pq, bn2_g, bn2_b, a2, c2, 2048);
    k_foldw_bf<false><<<1024, 256, 0, stream>>>(w2, b2, a2, c2, w2a, b2p, 2048, 1000);

    // ---- out = h @ w2a^T + b2p -> fp32 (128x256 tiles) ----
    gemm256<4, 2, 2><<<dim3(256), 512, 0, stream>>>(
        h, w2a, out, 2048, 4, 1000, 1000, b2p, nullptr, nullptr);
}

// Round 10
// 231.815 us; speedup vs baseline: 2.1051x; 1.2742x over previous
//
#include <hip/hip_runtime.h>
#include <math.h>

// B=8192, X=8, C=512, P=8, Y=1000, FAKE=16, F=2048, CLS=1000, IN_DIM=1024, SF=64
//
// Pipeline (12 launches; r5 structure, colstat vectorized):
//  k_prep:   texn = rownorm(tex_f)->bf16  |  g_bf = fake_cls @ fc_w ->bf16
//  logits[p] = g_bf[p] @ texn[p]^T            [MFMA128 EPI3, z=p]
//  k_wsum_sm: softmax(logits) fused, partial texa sums
//  k_texa_red: reduce -> texa bf16
//  cp' = (img @ texa^T) * inv_row             [MFMA128 EPI0, A fp32 reg-staged,
//                                              row-norm inline, out bf16, permuted cols]
//  k_colstat_v (bf16x8 vectorized) -> bnfin1 -> foldw1 (perm)
//  h = elu(cp' @ w1a^T + b1p)                 [gemm256 FM=8, r5 pipeline VERBATIM,
//                                              col-stats fused -> ps/pq (64 rows)]
//  bnfin2 -> foldw2 (pad 1024)
//  out = h @ w2a^T + b2p                      [gemm256 FM=4, fp32]

typedef __attribute__((ext_vector_type(8))) short bf16x8;
typedef __attribute__((ext_vector_type(4))) float f32x4;

__device__ __forceinline__ float waveSum(float v) {
#pragma unroll
    for (int o = 32; o > 0; o >>= 1) v += __shfl_xor(v, o);
    return v;
}
__device__ __forceinline__ float waveMax(float v) {
#pragma unroll
    for (int o = 32; o > 0; o >>= 1) v = fmaxf(v, __shfl_xor(v, o));
    return v;
}
__device__ __forceinline__ unsigned short f2bf(float x) {
    union { float f; unsigned u; } v; v.f = x;
    unsigned r = v.u + 0x7FFFu + ((v.u >> 16) & 1u);
    return (unsigned short)(r >> 16);
}
__device__ __forceinline__ float bf2f(unsigned short h) {
    union { unsigned u; float f; } v; v.u = ((unsigned)h) << 16; return v.f;
}
__device__ __forceinline__ float bf2f_s(short h) { return bf2f((unsigned short)h); }
__device__ __forceinline__ void gload16(const void* g, const void* l) {
    __builtin_amdgcn_global_load_lds((const __attribute__((address_space(1))) void*)g,
                                     (__attribute__((address_space(3))) void*)l, 16, 0, 0);
}
__device__ __forceinline__ int xcd_swz(int d, int n) {
    int q = n >> 3;                     // all gemm grids are %8==0
    return (d & 7) * q + (d >> 3);
}
#define SBAR __builtin_amdgcn_sched_barrier(0)

// ---------- fused: rownorm(tex_f)->texn bf16 (blocks 0..7999), g_bf (8000..8127) ----------
__global__ __launch_bounds__(256) void k_prep(const float* __restrict__ tex_f,
                                              unsigned short* __restrict__ texn,
                                              const float* __restrict__ fake_cls,
                                              const float* __restrict__ fc_w,
                                              unsigned short* __restrict__ g_bf) {
    __shared__ float sred[4];
    __shared__ float fcls[512];
    int bid = blockIdx.x, t = threadIdx.x;
    if (bid < 8000) {
        const float* r = tex_f + (size_t)bid * 512;
        float2 v = *(const float2*)(r + t * 2);
        float ss = v.x * v.x + v.y * v.y;
        ss = waveSum(ss);
        if ((t & 63) == 0) sred[t >> 6] = ss;
        __syncthreads();
        float tot = sred[0] + sred[1] + sred[2] + sred[3];
        float sc = 64.f / (sqrtf(tot) + 1e-6f);
        unsigned u = (unsigned)f2bf(v.x * sc) | ((unsigned)f2bf(v.y * sc) << 16);
        *(unsigned*)(texn + (size_t)bid * 512 + t * 2) = u;
    } else {
        int row = bid - 8000;
        fcls[t]       = fake_cls[row * 512 + t];
        fcls[t + 256] = fake_cls[row * 512 + t + 256];
        __syncthreads();
        float a0 = 0.f, a1 = 0.f;
        for (int d = 0; d < 512; ++d) {
            float fv = fcls[d];
            a0 = fmaf(fv, fc_w[d * 512 + t], a0);
            a1 = fmaf(fv, fc_w[d * 512 + t + 256], a1);
        }
        g_bf[row * 512 + t]       = f2bf(a0);
        g_bf[row * 512 + t + 256] = f2bf(a1);
    }
}

// ---------- wsum with fused softmax: block (yt 0..15, p 0..7) ----------
__global__ __launch_bounds__(256) void k_wsum_sm(const float* __restrict__ logit,
                                                 const unsigned short* __restrict__ texn,
                                                 float* __restrict__ part) {
    int yt = blockIdx.x, p = blockIdx.y, t = threadIdx.x;
    int lane = t & 63, w = t >> 6;
    __shared__ float wl[16][63];
    __shared__ float ms[16], iss[16];
    const int y0 = yt * 63;
    const int ylen = min(63, 1000 - y0);
#pragma unroll
    for (int rr = 0; rr < 4; ++rr) {
        int x = w * 4 + rr;
        const float* lr = logit + ((size_t)p * 16 + x) * 1000;
        float m = -3.0e38f;
        for (int y = lane; y < 1000; y += 64) m = fmaxf(m, lr[y]);
        m = waveMax(m);
        float s = 0.f;
        for (int y = lane; y < 1000; y += 64) s += expf(lr[y] - m);
        s = waveSum(s);
        if (lane == 0) { ms[x] = m; iss[x] = 1.f / s; }
    }
    __syncthreads();
    for (int idx = t; idx < 16 * ylen; idx += 256) {
        int x = idx / ylen, y = idx % ylen;
        wl[x][y] = expf(logit[((size_t)p * 16 + x) * 1000 + y0 + y] - ms[x]) * iss[x];
    }
    __syncthreads();
    int c0 = t * 2;
    const unsigned short* tp = texn + ((size_t)p * 1000 + y0) * 512 + c0;
    float a0[16], a1[16];
#pragma unroll
    for (int x = 0; x < 16; ++x) { a0[x] = 0.f; a1[x] = 0.f; }
    for (int y = 0; y < ylen; ++y) {
        unsigned u = *(const unsigned*)(tp + (size_t)y * 512);
        float lo = bf2f((unsigned short)(u & 0xffff));
        float hi = bf2f((unsigned short)(u >> 16));
#pragma unroll
        for (int x = 0; x < 16; ++x) {
            float ww = wl[x][y];
            a0[x] = fmaf(ww, lo, a0[x]);
            a1[x] = fmaf(ww, hi, a1[x]);
        }
    }
#pragma unroll
    for (int x = 0; x < 16; ++x) {
        float* dst = part + ((size_t)((yt * 8 + p) * 16 + x)) * 512 + c0;
        dst[0] = a0[x];
        dst[1] = a1[x];
    }
}

// ---------- reduce 16 y-partials -> texa bf16 ----------
__global__ __launch_bounds__(256) void k_texa_red(const float* __restrict__ part,
                                                  unsigned short* __restrict__ texa) {
    int row = blockIdx.x, t = threadIdx.x;      // row = p*16 + x
    int p = row >> 4, x = row & 15;
    int c = t * 2;
    float s0 = 0.f, s1 = 0.f;
#pragma unroll
    for (int yt = 0; yt < 16; ++yt) {
        const float* src = part + ((size_t)((yt * 8 + p) * 16 + x)) * 512 + c;
        s0 += src[0];
        s1 += src[1];
    }
    unsigned u = (unsigned)f2bf(s0) | ((unsigned)f2bf(s1) << 16);
    *(unsigned*)(texa + (size_t)row * 512 + c) = u;
}

// ---------- vectorized column stats over cp (8192x1024 bf16) ----------
// grid (8, 64): x = 128-col block, y = 128-row block. bf16x8 (16B) loads,
// 16 row-groups x 8 rows per thread, LDS merge -> ps/pq[64][1024].
__global__ __launch_bounds__(256) void k_colstat_v(const unsigned short* __restrict__ src,
                                                   float* __restrict__ ps,
                                                   float* __restrict__ pq) {
    const int cb = blockIdx.x, rb = blockIdx.y, t = threadIdx.x;
    const int tc = t & 15;      // 16 col groups of 8 cols
    const int tg = t >> 4;      // 16 row groups of 8 rows
    const unsigned short* base =
        src + (size_t)(rb * 128 + tg * 8) * 1024 + cb * 128 + tc * 8;
    float s[8], q[8];
#pragma unroll
    for (int j = 0; j < 8; ++j) { s[j] = 0.f; q[j] = 0.f; }
#pragma unroll
    for (int r = 0; r < 8; ++r) {
        bf16x8 v = *(const bf16x8*)(base + (size_t)r * 1024);
#pragma unroll
        for (int j = 0; j < 8; ++j) {
            float f = bf2f_s(v[j]);
            s[j] += f;
            q[j] = fmaf(f, f, q[j]);
        }
    }
    __shared__ float ls[16][128];
    __shared__ float lq[16][128];
#pragma unroll
    for (int j = 0; j < 8; ++j) { ls[tg][tc * 8 + j] = s[j]; lq[tg][tc * 8 + j] = q[j]; }
    __syncthreads();
    if (t < 128) {
        float S = 0.f, Q = 0.f;
#pragma unroll
        for (int g = 0; g < 16; ++g) { S += ls[g][t]; Q += lq[g][t]; }
        ps[(size_t)rb * 1024 + cb * 128 + t] = S;
        pq[(size_t)rb * 1024 + cb * 128 + t] = Q;
    }
}

// ---------- finalize BN scale/shift; PERM maps permuted col' -> true j ----------
template <bool PERM>
__global__ __launch_bounds__(256) void k_bnfin(const float* __restrict__ ps,
                                               const float* __restrict__ pq,
                                               const float* __restrict__ gam,
                                               const float* __restrict__ bet,
                                               float* __restrict__ a, float* __restrict__ c,
                                               int ncols) {
    int col = blockIdx.x * 256 + threadIdx.x;
    float S = 0.f, Q = 0.f;
    for (int i = 0; i < 64; ++i) {
        S += ps[(size_t)i * ncols + col];
        Q += pq[(size_t)i * ncols + col];
    }
    float mean = S * (1.f / 8192.f);
    float var = Q * (1.f / 8192.f) - mean * mean;
    int j = col;
    if (PERM) {
        int x = col >> 7, jj = col & 127, pp = jj >> 4, d = jj & 15;
        j = (pp << 7) + (x << 4) + d;
    }
    float av = gam[j] * rsqrtf(var + 1e-5f);
    a[col] = av;
    c[col] = bet[j] - mean * av;
}

// ---------- fold BN into weights -> bf16 ----------
template <bool PERM>
__global__ __launch_bounds__(256) void k_foldw_bf(const float* __restrict__ W,
                                                  const float* __restrict__ bin,
                                                  const float* __restrict__ a,
                                                  const float* __restrict__ c,
                                                  unsigned short* __restrict__ Wout,
                                                  float* __restrict__ bout,
                                                  int Kdim, int nvalid) {
    int f = blockIdx.x, t = threadIdx.x;
    unsigned short* wo = Wout + (size_t)f * Kdim;
    if (f >= nvalid) {
        for (int col = t; col < Kdim; col += 256) wo[col] = 0;
        if (t == 0) bout[f] = 0.f;
        return;
    }
    const float* wr = W + (size_t)f * Kdim;
    float partial = 0.f;
    for (int col = t; col < Kdim; col += 256) {
        int j = col;
        if (PERM) {
            int x = col >> 7, jj = col & 127, pp = jj >> 4, d = jj & 15;
            j = (pp << 7) + (x << 4) + d;
        }
        float wv = wr[j];
        wo[col] = f2bf(wv * a[col]);
        partial = fmaf(wv, c[col], partial);
    }
    partial = waveSum(partial);
    __shared__ float sred[4];
    if ((t & 63) == 0) sred[t >> 6] = partial;
    __syncthreads();
    if (t == 0) bout[f] = bin[f] + sred[0] + sred[1] + sred[2] + sred[3];
}

// ---------- small MFMA GEMM (128x128 tile, 4 waves) for cp & logits ----------
// EPI 0 (A_F32): bf16 store * rowinv computed inline from A's fp32 rows (cp)
// EPI 3: fp32 store, col<nvalid, row<16 (logits, batched over z=p)
template <int EPI, bool A_F32>
__global__ __launch_bounds__(256) void gemm_mfma(const void* __restrict__ Av,
                                                 const unsigned short* __restrict__ Bv,
                                                 void* __restrict__ Cv, int K,
                                                 int ntn, int ldc, int nvalid,
                                                 int aZ, int bZ, int cZ) {
    __shared__ unsigned short Asl[128 * 64];
    __shared__ unsigned short Bsl[128 * 64];
    __shared__ float rowinv[128];
    const int tid = threadIdx.x;
    const int lane = tid & 63, wid = tid >> 6;
    const int wr = wid >> 1, wc = wid & 1;
    const int wg = xcd_swz(blockIdx.x, gridDim.x);
    const int m0 = (wg / ntn) * 128, n0 = (wg % ntn) * 128;
    const int z = blockIdx.y;

    const float* Af = (const float*)Av;
    const unsigned short* Ab = (const unsigned short*)Av + (size_t)z * aZ;
    const unsigned short* B = Bv + (size_t)z * bZ;

    f32x4 acc[4][4];
#pragma unroll
    for (int i = 0; i < 4; ++i)
#pragma unroll
        for (int j = 0; j < 4; ++j) acc[i][j] = {0.f, 0.f, 0.f, 0.f};

    const int swz = ((lane & 7) ^ (lane >> 3)) * 8;
    const int lrow = lane & 15, lkh = lane >> 4;
    float ssq[4] = {0.f, 0.f, 0.f, 0.f};

    for (int k0 = 0; k0 < K; k0 += 64) {
        if (A_F32) {
#pragma unroll
            for (int r = 0; r < 4; ++r) {
                int row = r * 32 + (tid >> 3);
                int kk = (tid & 7) * 8;
                const float* src = Af + (size_t)(m0 + row) * K + k0 + kk;
                float4 p0 = *(const float4*)src;
                float4 p1 = *(const float4*)(src + 4);
                ssq[r] += p0.x*p0.x + p0.y*p0.y + p0.z*p0.z + p0.w*p0.w
                        + p1.x*p1.x + p1.y*p1.y + p1.z*p1.z + p1.w*p1.w;
                bf16x8 v;
                v[0] = (short)f2bf(p0.x); v[1] = (short)f2bf(p0.y);
                v[2] = (short)f2bf(p0.z); v[3] = (short)f2bf(p0.w);
                v[4] = (short)f2bf(p1.x); v[5] = (short)f2bf(p1.y);
                v[6] = (short)f2bf(p1.z); v[7] = (short)f2bf(p1.w);
                *(bf16x8*)&Asl[row * 64 + (kk ^ ((row & 7) << 3))] = v;
            }
        } else {
#pragma unroll
            for (int r = 0; r < 4; ++r) {
                int row = r * 32 + wid * 8 + (lane >> 3);
                gload16(Ab + (size_t)(m0 + row) * K + k0 + swz,
                        Asl + r * 2048 + wid * 512);
            }
        }
#pragma unroll
        for (int r = 0; r < 4; ++r) {
            int row = r * 32 + wid * 8 + (lane >> 3);
            gload16(B + (size_t)(n0 + row) * K + k0 + swz,
                    Bsl + r * 2048 + wid * 512);
        }
        __syncthreads();
#pragma unroll
        for (int kk = 0; kk < 2; ++kk) {
            bf16x8 af[4], bfr[4];
#pragma unroll
            for (int m = 0; m < 4; ++m) {
                int row = wr * 64 + m * 16 + lrow;
                af[m] = *(const bf16x8*)&Asl[row * 64 + ((kk * 32 + lkh * 8) ^ ((row & 7) << 3))];
            }
#pragma unroll
            for (int n = 0; n < 4; ++n) {
                int row = wc * 64 + n * 16 + lrow;
                bfr[n] = *(const bf16x8*)&Bsl[row * 64 + ((kk * 32 + lkh * 8) ^ ((row & 7) << 3))];
            }
#pragma unroll
            for (int m = 0; m < 4; ++m)
#pragma unroll
                for (int n = 0; n < 4; ++n)
                    acc[m][n] = __builtin_amdgcn_mfma_f32_16x16x32_bf16(af[m], bfr[n], acc[m][n], 0, 0, 0);
        }
        __syncthreads();
    }

    if (A_F32) {
#pragma unroll
        for (int r = 0; r < 4; ++r) {
            float s = ssq[r];
            s += __shfl_xor(s, 1); s += __shfl_xor(s, 2); s += __shfl_xor(s, 4);
            if ((tid & 7) == 0) rowinv[r * 32 + (tid >> 3)] = 64.f / (sqrtf(s) + 1e-6f);
        }
        __syncthreads();
    }

    const int colbase = n0 + wc * 64 + lrow;
    if (EPI == 0) {
        unsigned short* C = (unsigned short*)Cv;
#pragma unroll
        for (int m = 0; m < 4; ++m) {
            int rloc = wr * 64 + m * 16 + lkh * 4;
#pragma unroll
            for (int r = 0; r < 4; ++r) {
                float riv = rowinv[rloc + r];
#pragma unroll
                for (int n = 0; n < 4; ++n)
                    C[(size_t)(m0 + rloc + r) * ldc + colbase + n * 16] = f2bf(acc[m][n][r] * riv);
            }
        }
    } else {
        float* C = (float*)Cv + (size_t)z * cZ;
#pragma unroll
        for (int m = 0; m < 4; ++m) {
            int row = m0 + wr * 64 + m * 16 + lkh * 4;
#pragma unroll
            for (int r = 0; r < 4; ++r) {
                if ((row + r) >= 16) continue;
#pragma unroll
                for (int n = 0; n < 4; ++n) {
                    int col = colbase + n * 16;
                    if (col < nvalid) C[(size_t)(row + r) * ldc + col] = acc[m][n][r];
                }
            }
        }
    }
}

// ---------- big MFMA GEMM: r5-verified counted-vmcnt pipeline, 8 waves (VERBATIM r5) ----------
// BM = FM*32 (FM=8 -> 256, FM=4 -> 128), BN = NH*128 (=256).
// Waves: 2(M) x 4(N); per-wave output = (BM/2) x 64 = FM x 4 frags of 16x16.
// Schedule per K-tile kt (buffers buf[kt&1], 2-deep prefetch):
//   ds_read kk0 frags -> MFMA kk0 -> ds_read kk1 frags
//   lgkmcnt(0); s_barrier            // all waves' reads of buf[cur] retired
//   stage(kt+2 -> buf[cur]); s_waitcnt vmcnt(LA)   // kt+1 landed; kt+2 in flight
//   s_barrier                        // buf[cur^1] globally ready
//   MFMA kk1 (register-only; overlaps kt+2 flight & next iter's reads)
// EPI 1: bf16 elu(x+bias), col stats -> ps/pq[(mt*2+wm)][col]
// EPI 2: fp32 x+bias, col<nvalid
template <int FM, int NH, int EPI>
__global__ __launch_bounds__(512, 2) void gemm256(const unsigned short* __restrict__ A,
                                                  const unsigned short* __restrict__ B,
                                                  void* __restrict__ Cv, int K,
                                                  int ntn, int ldc, int nvalid,
                                                  const float* __restrict__ bias,
                                                  float* __restrict__ ps,
                                                  float* __restrict__ pq) {
    constexpr int BM = FM * 32;
    constexpr int MH = BM / 128;
    constexpr int LA = 2 * (MH + NH);   // gloads per thread per K-tile
    __shared__ unsigned short Asl[2][MH][128 * 64];
    __shared__ unsigned short Bsl[2][NH][128 * 64];
    const int tid = threadIdx.x;
    const int lane = tid & 63, wid = tid >> 6;
    const int wm = wid >> 2, wn = wid & 3;
    const int wg = xcd_swz(blockIdx.x, gridDim.x);
    const int m0 = (wg / ntn) * BM, n0 = (wg % ntn) * 256;
    const int lrow = lane & 15, lkh = lane >> 4;
    const int l7 = lane & 7;
    const int ksrc = ((lane & 7) ^ (lane >> 3)) * 8;
    const int mbase = wm * (BM / 2);
    const int mhalf = mbase >> 7;
    const int mloc0 = mbase & 127;
    const int nbase = wn * 64;
    const int nhalf = nbase >> 7;
    const int nloc0 = nbase & 127;

    f32x4 acc[FM][4];
#pragma unroll
    for (int m = 0; m < FM; ++m)
#pragma unroll
        for (int n = 0; n < 4; ++n) acc[m][n] = {0.f, 0.f, 0.f, 0.f};

    const int nkt = K >> 6;

    auto stage = [&](int kt, int buf) {
#pragma unroll
        for (int hf = 0; hf < MH; ++hf)
#pragma unroll
            for (int j = 0; j < 2; ++j) {
                int rl = wid * 16 + j * 8 + (lane >> 3);
                gload16(A + (size_t)(m0 + hf * 128 + rl) * K + kt * 64 + ksrc,
                        &Asl[buf][hf][(wid * 16 + j * 8) * 64]);
            }
#pragma unroll
        for (int hf = 0; hf < NH; ++hf)
#pragma unroll
            for (int j = 0; j < 2; ++j) {
                int rl = wid * 16 + j * 8 + (lane >> 3);
                gload16(B + (size_t)(n0 + hf * 128 + rl) * K + kt * 64 + ksrc,
                        &Bsl[buf][hf][(wid * 16 + j * 8) * 64]);
            }
    };

    // prologue: fill both buffers; wait for buf0 only (buf1 stays in flight)
    stage(0, 0);
    stage(1, 1);
    if constexpr (LA == 8) asm volatile("s_waitcnt vmcnt(8)" ::: "memory");
    else asm volatile("s_waitcnt vmcnt(6)" ::: "memory");
    SBAR; __builtin_amdgcn_s_barrier(); SBAR;

    for (int kt = 0; kt < nkt; ++kt) {
        const int cur = kt & 1;
        // ---- kk0 fragment reads ----
        bf16x8 af0[FM], bf0[4];
#pragma unroll
        for (int m = 0; m < FM; ++m) {
            int row = mloc0 + m * 16 + lrow;
            af0[m] = *(const bf16x8*)&Asl[cur][mhalf][row * 64 + ((lkh ^ l7) << 3)];
        }
#pragma unroll
        for (int n = 0; n < 4; ++n) {
            int row = nloc0 + n * 16 + lrow;
            bf0[n] = *(const bf16x8*)&Bsl[cur][nhalf][row * 64 + ((lkh ^ l7) << 3)];
        }
        // ---- kk0 MFMA ----
        __builtin_amdgcn_s_setprio(1);
#pragma unroll
        for (int m = 0; m < FM; ++m)
#pragma unroll
            for (int n = 0; n < 4; ++n)
                acc[m][n] = __builtin_amdgcn_mfma_f32_16x16x32_bf16(af0[m], bf0[n], acc[m][n], 0, 0, 0);
        __builtin_amdgcn_s_setprio(0);
        // ---- kk1 fragment reads ----
        bf16x8 af1[FM], bf1[4];
#pragma unroll
        for (int m = 0; m < FM; ++m) {
            int row = mloc0 + m * 16 + lrow;
            af1[m] = *(const bf16x8*)&Asl[cur][mhalf][row * 64 + (((4 + lkh) ^ l7) << 3)];
        }
#pragma unroll
        for (int n = 0; n < 4; ++n) {
            int row = nloc0 + n * 16 + lrow;
            bf1[n] = *(const bf16x8*)&Bsl[cur][nhalf][row * 64 + (((4 + lkh) ^ l7) << 3)];
        }
        if (kt + 1 < nkt) {
            asm volatile("s_waitcnt lgkmcnt(0)" ::: "memory");
            SBAR; __builtin_amdgcn_s_barrier(); SBAR;
            if (kt + 2 < nkt) {
                stage(kt + 2, cur);
                if constexpr (LA == 8) asm volatile("s_waitcnt vmcnt(8)" ::: "memory");
                else asm volatile("s_waitcnt vmcnt(6)" ::: "memory");
            } else {
                asm volatile("s_waitcnt vmcnt(0)" ::: "memory");
            }
            SBAR; __builtin_amdgcn_s_barrier(); SBAR;
        }
        // ---- kk1 MFMA (register-only; overlaps kt+2 flight & next reads) ----
        __builtin_amdgcn_s_setprio(1);
#pragma unroll
        for (int m = 0; m < FM; ++m)
#pragma unroll
            for (int n = 0; n < 4; ++n)
                acc[m][n] = __builtin_amdgcn_mfma_f32_16x16x32_bf16(af1[m], bf1[n], acc[m][n], 0, 0, 0);
        __builtin_amdgcn_s_setprio(0);
    }

    // ---- epilogue ----
    const int colbase = n0 + nbase + lrow;
    if (EPI == 1) {
        unsigned short* C = (unsigned short*)Cv;
        float bv[4], sN[4] = {0.f, 0.f, 0.f, 0.f}, qN[4] = {0.f, 0.f, 0.f, 0.f};
#pragma unroll
        for (int n = 0; n < 4; ++n) bv[n] = bias[colbase + n * 16];
#pragma unroll
        for (int m = 0; m < FM; ++m) {
            int row = m0 + mbase + m * 16 + lkh * 4;
#pragma unroll
            for (int r = 0; r < 4; ++r)
#pragma unroll
                for (int n = 0; n < 4; ++n) {
                    float v = acc[m][n][r] + bv[n];
                    v = v > 0.f ? v : expm1f(v);
                    sN[n] += v;
                    qN[n] = fmaf(v, v, qN[n]);
                    C[(size_t)(row + r) * ldc + colbase + n * 16] = f2bf(v);
                }
        }
#pragma unroll
        for (int n = 0; n < 4; ++n) {
            sN[n] += __shfl_xor(sN[n], 16); sN[n] += __shfl_xor(sN[n], 32);
            qN[n] += __shfl_xor(qN[n], 16); qN[n] += __shfl_xor(qN[n], 32);
        }
        if (lane < 16) {
            int mt = wg / ntn;
#pragma unroll
            for (int n = 0; n < 4; ++n) {
                ps[(size_t)(mt * 2 + wm) * ldc + colbase + n * 16] = sN[n];
                pq[(size_t)(mt * 2 + wm) * ldc + colbase + n * 16] = qN[n];
            }
        }
    } else {
        float* C = (float*)Cv;
        float bv[4];
#pragma unroll
        for (int n = 0; n < 4; ++n) bv[n] = bias[colbase + n * 16];
#pragma unroll
        for (int m = 0; m < FM; ++m) {
            int row = m0 + mbase + m * 16 + lkh * 4;
#pragma unroll
            for (int r = 0; r < 4; ++r)
#pragma unroll
                for (int n = 0; n < 4; ++n) {
                    int col = colbase + n * 16;
                    if (col < nvalid) C[(size_t)(row + r) * ldc + col] = acc[m][n][r] + bv[n];
                }
        }
    }
}

// ---------------- launch ----------------
extern "C" void kernel_launch(void* const* d_in, const int* in_sizes, int n_in,
                              void* d_out, int out_size, void* d_ws, size_t ws_size,
                              hipStream_t stream) {
    const float* img_f    = (const float*)d_in[0];   // (8192,8,512)
    const float* tex_f    = (const float*)d_in[1];   // (8,1000,512)
    const float* fake_cls = (const float*)d_in[2];   // (8,16,512)
    const float* fc_w     = (const float*)d_in[3];   // (512,512)
    const float* bn1_g    = (const float*)d_in[5];   // (1024)
    const float* bn1_b    = (const float*)d_in[6];
    const float* w1       = (const float*)d_in[7];   // (2048,1024)
    const float* b1       = (const float*)d_in[8];
    const float* bn2_g    = (const float*)d_in[9];   // (2048)
    const float* bn2_b    = (const float*)d_in[10];
    const float* w2       = (const float*)d_in[11];  // (1000,2048)
    const float* b2       = (const float*)d_in[12];
    float* out = (float*)d_out;

    char* w = (char*)d_ws;   // byte offsets; total ~73.3 MB
    unsigned short* texn = (unsigned short*)(w);             // 8,388,608 (8000 rows + pad)
    unsigned short* g_bf = (unsigned short*)(w + 8388608);   //   262,144 (128 rows + pad)
    float*          logit= (float*)(w + 8650752);            //   524,288 (128x1000)
    float*          part = (float*)(w + 9175040);            // 4,194,304 (16x8x16x512)
    unsigned short* texa = (unsigned short*)(w + 13369344);  //   131,072
    unsigned short* cp   = (unsigned short*)(w + 13500416);  // 16,777,216
    unsigned short* w1a  = (unsigned short*)(w + 30277632);  //  4,194,304
    float*          b1p  = (float*)(w + 34471936);           //      8,192
    float*          a1   = (float*)(w + 34480128);
    float*          c1   = (float*)(w + 34484224);
    float*          ps   = (float*)(w + 34488320);           //    524,288
    float*          pq   = (float*)(w + 35012608);           //    524,288
    unsigned short* h    = (unsigned short*)(w + 35536896);  // 33,554,432
    unsigned short* w2a  = (unsigned short*)(w + 69091328);  //  4,194,304
    float*          b2p  = (float*)(w + 73285632);
    float*          a2   = (float*)(w + 73289728);
    float*          c2   = (float*)(w + 73297920);

    // ---- attention path ----
    k_prep<<<8128, 256, 0, stream>>>(tex_f, texn, fake_cls, fc_w, g_bf);
    gemm_mfma<3, false><<<dim3(8, 8), 256, 0, stream>>>(
        g_bf, texn, logit, 512, 8, 1000, 1000, 16 * 512, 1000 * 512, 16 * 1000);
    k_wsum_sm<<<dim3(16, 8), 256, 0, stream>>>(logit, texn, part);
    k_texa_red<<<128, 256, 0, stream>>>(part, texa);

    // ---- cp' = (img @ texa^T)*inv -> bf16, permuted cols (65536 x 128) ----
    gemm_mfma<0, true><<<dim3(512, 1), 256, 0, stream>>>(
        img_f, texa, cp, 512, 1, 128, 128, 0, 0, 0);

    // ---- BN1: vectorized stats -> bnfin1 -> fold into w1 (column permutation) ----
    k_colstat_v<<<dim3(8, 64), 256, 0, stream>>>(cp, ps, pq);
    k_bnfin<true><<<4, 256, 0, stream>>>(ps, pq, bn1_g, bn1_b, a1, c1, 1024);
    k_foldw_bf<true><<<2048, 256, 0, stream>>>(w1, b1, a1, c1, w1a, b1p, 1024, 2048);

    // ---- h = elu(cp' @ w1a^T + b1p) -> bf16, col-stats fused (256x256 tiles) ----
    gemm256<8, 2, 1><<<dim3(256), 512, 0, stream>>>(
        cp, w1a, h, 1024, 8, 2048, 2048, b1p, ps, pq);

    // ---- BN2 -> fold into w2 (pad rows to 1024) ----
    k_bnfin<false><<<8, 256, 0, stream>>>(ps, pq, bn2_g, bn2_b, a2, c2, 2048);
    k_foldw_bf<false><<<1024, 256, 0, stream>>>(w2, b2, a2, c2, w2a, b2p, 2048, 1000);

    // ---- out = h @ w2a^T + b2p -> fp32 (128x256 tiles) ----
    gemm256<4, 2, 2><<<dim3(256), 512, 0, stream>>>(
        h, w2a, out, 2048, 4, 1000, 1000, b2p, nullptr, nullptr);
}